// Round 7
// baseline (1149.652 us; speedup 1.0000x reference)
//
#include <hip/hip_runtime.h>
#include <hip/hip_bf16.h>

#define DD 4096
#define NTOK 8192

using u16 = unsigned short;

typedef __attribute__((ext_vector_type(8))) short bfrag;   // 8 bf16 = 4 VGPR
typedef __attribute__((ext_vector_type(4))) int i32x4;     // 16 i8 or 4 i32
typedef __attribute__((ext_vector_type(4))) float ffrag;   // 4 f32 (MFMA C/D)
typedef __attribute__((ext_vector_type(4))) float f32x4v;

// RNE float -> bf16 (bit math; matches numpy/JAX round-to-nearest-even)
__device__ __forceinline__ u16 f2bf(float f) {
  unsigned u = __float_as_uint(f);
  u += 0x7FFFu + ((u >> 16) & 1u);
  return (u16)(u >> 16);
}
__device__ __forceinline__ float bf2f(u16 u) {
  return __uint_as_float(((unsigned)u) << 16);
}
__device__ __forceinline__ char q8(float v, float s) {
  float r = rintf(v * s);
  r = fminf(fmaxf(r, -127.f), 127.f);
  return (char)(int)r;
}

#define GLDS16(g, l)                                                  \
  __builtin_amdgcn_global_load_lds(                                   \
      (__attribute__((address_space(1))) const void*)(g),             \
      (__attribute__((address_space(3))) void*)(l), 16, 0, 0)

#define MEMFENCE() asm volatile("" ::: "memory")

// ------- prep x: f32 -> x_hi bf16, x_lo8 i8*2^13, x_hi8 i8*2^4 -------
__global__ void __launch_bounds__(256) prep_x_kernel(
    const float* __restrict__ in, u16* __restrict__ hi,
    char* __restrict__ lo8, char* __restrict__ hi8, long n4) {
  long i = (long)blockIdx.x * blockDim.x + threadIdx.x;
  const long stride = (long)gridDim.x * blockDim.x;
  for (; i < n4; i += stride) {
    f32x4v v = reinterpret_cast<const f32x4v*>(in)[i];
    ushort4 hv; char4 lv, xv;
#pragma unroll
    for (int j = 0; j < 4; ++j) {
      float f = v[j];
      u16 hb = f2bf(f);
      float xl = f - bf2f(hb);
      ((u16*)&hv)[j] = hb;
      ((char*)&lv)[j] = q8(xl, 8192.f);   // 2^13
      ((char*)&xv)[j] = q8(f, 16.f);      // 2^4
    }
    reinterpret_cast<ushort4*>(hi)[i] = hv;
    reinterpret_cast<char4*>(lo8)[i] = lv;
    reinterpret_cast<char4*>(hi8)[i] = xv;
  }
}

// ------- prep Pi: f32 -> p_hi bf16, p_hi8 i8*2^10, p_lo8 i8*2^19 -------
__global__ void __launch_bounds__(256) prep_pi_kernel(
    const float* __restrict__ in, u16* __restrict__ hi,
    char* __restrict__ hi8, char* __restrict__ lo8, long n4) {
  long i = (long)blockIdx.x * blockDim.x + threadIdx.x;
  const long stride = (long)gridDim.x * blockDim.x;
  for (; i < n4; i += stride) {
    f32x4v v = reinterpret_cast<const f32x4v*>(in)[i];
    ushort4 hv; char4 hq, lq;
#pragma unroll
    for (int j = 0; j < 4; ++j) {
      float f = v[j];
      u16 hb = f2bf(f);
      float pl = f - bf2f(hb);
      ((u16*)&hv)[j] = hb;
      ((char*)&hq)[j] = q8(f, 1024.f);      // 2^10
      ((char*)&lq)[j] = q8(pl, 524288.f);   // 2^19
    }
    reinterpret_cast<ushort4*>(hi)[i] = hv;
    reinterpret_cast<char4*>(hi8)[i] = hq;
    reinterpret_cast<char4*>(lo8)[i] = lq;
  }
}

// ---------------- transpose f32 [R][C] -> bf16 [C][R] ----------------
__global__ void __launch_bounds__(256) transpose_bf16_kernel(
    const float* __restrict__ in, u16* __restrict__ out, int R, int C) {
  __shared__ u16 tile[64][65];
  const int bc = blockIdx.x << 6;
  const int br = blockIdx.y << 6;
  const int tc = threadIdx.x & 63;
  const int tr0 = threadIdx.x >> 6;
#pragma unroll
  for (int p = 0; p < 16; ++p) {
    int r = tr0 + (p << 2);
    tile[tc][r] = f2bf(in[(size_t)(br + r) * C + (bc + tc)]);
  }
  __syncthreads();
#pragma unroll
  for (int p = 0; p < 16; ++p) {
    int orow = tr0 + (p << 2);
    out[(size_t)(bc + orow) * R + (br + tc)] = tile[orow][tc];
  }
}

// ====== GEMM1 hybrid bf16+i8:  y = xh@ph^T (bf16 MFMA)
//                                 + [xl8|xh8]@[ph8|pl8]^T (i8 K=64 MFMA) * 2^-23
// Scales: xl*2^13 * ph*2^10 = 2^23 ; xh*2^4 * pl*2^19 = 2^23 (shared acc).
// Block 256x128, 8 waves (4M x 2N), per-wave 64x64: acc_hh 64 f32 + acc_lo
// 64 i32. BK=32; units/tile: Ah 16K (bf16), A8 16K (i8 concat [xl|xh], 64B
// rows), Bh 8K, B8 8K -> 48KB, dbuf 96KB. Grid 1024 (%8==0).
// 2 phases/tile: P0 {16 ds_reads, stage A[t+1], bar, 16 bf16-MFMA,
// lgkmcnt(0), bar}; P1 {stage B[t+2], bar, 16 i8-MFMA, vmcnt(2), bar}.
// Swizzle (64B rows): byte ^= ((byte>>7)&3)<<4 -> per-8-row slot-mod-8 is a
// permutation (conflict-free); inverse-applied to global sources (linear
// gload_lds dest), applied on ds_read addrs. lgkmcnt(0) before P0-end bar
// makes stageB's overwrite of the i8-read regions safe; vmcnt(2)/tile
// (vmcnt(0) at t>=126 tail) covers all cross-tile RAW (A[t+1],B[t+1] landed).
__global__ void __launch_bounds__(512, 2) gemm_i8lo_kernel(
    const u16* __restrict__ xh, const char* __restrict__ xl8,
    const char* __restrict__ xh8, const u16* __restrict__ ph,
    const char* __restrict__ ph8, const char* __restrict__ pl8,
    u16* __restrict__ Yq, const float* __restrict__ cent, int M, int N) {
  __shared__ __align__(16) char SM[98304];
  __shared__ float clut[16];
  const int tid = threadIdx.x;
  if (tid < 16) clut[tid] = cent[tid];

  const int nbn = N >> 7;                    // 32
  const int nwg = (M >> 8) * nbn;            // 1024
  int wg = blockIdx.x;
  wg = (wg & 7) * (nwg >> 3) + (wg >> 3);    // XCD swizzle, bijective
  const int tm = (wg / nbn) << 8;
  const int tn = (wg % nbn) << 7;

  const int lane = tid & 63;
  const int wv = tid >> 6;
  const int wm = wv >> 1;  // 0..3 row panel (64 rows)
  const int wn = wv & 1;   // 0..1 col panel (64 cols)
  const int l15 = lane & 15;
  const int kslc = lane >> 4;

  // ---- staging source precompute (dest linear, source pre-unswizzled)
  const int D0 = tid * 16, D1 = D0 + 8192;
  const int L0 = D0 ^ (((D0 >> 7) & 3) << 4);
  const int L1 = D1 ^ (((D1 >> 7) & 3) << 4);
  const int row0 = D0 >> 6, row1 = D1 >> 6;   // 0..127 / 128..255
  const int colE0 = (L0 & 63) >> 1, colE1 = (L1 & 63) >> 1;
  const int sel0 = (L0 & 63) >> 5, col80 = L0 & 31;
  const int sel1 = (L1 & 63) >> 5, col81 = L1 & 31;

  const u16* pAh0 = xh + (size_t)(tm + row0) * 4096 + colE0;
  const u16* pAh1 = xh + (size_t)(tm + row1) * 4096 + colE1;
  const char* pA80 = (sel0 ? xh8 : xl8) + (size_t)(tm + row0) * 4096 + col80;
  const char* pA81 = (sel1 ? xh8 : xl8) + (size_t)(tm + row1) * 4096 + col81;
  const u16* pBh = ph + (size_t)(tn + row0) * 4096 + colE0;   // row0 < 128
  const char* pB8 = (sel0 ? pl8 : ph8) + (size_t)(tn + row0) * 4096 + col80;

  auto stageA = [&](int tau) {
    if (tau >= 128) return;
    char* base = SM + (tau & 1) * 49152;
    const int o = tau * 32;  // 32 elems (=64B bf16 / 32B i8) per tile
    GLDS16(pAh0 + o, base + D0);
    GLDS16(pAh1 + o, base + D0 + 8192);
    GLDS16(pA80 + o, base + 16384 + D0);
    GLDS16(pA81 + o, base + 16384 + D0 + 8192);
  };
  auto stageB = [&](int tau) {
    if (tau >= 128) return;
    char* base = SM + (tau & 1) * 49152;
    const int o = tau * 32;
    GLDS16(pBh + o, base + 32768 + D0);
    GLDS16(pB8 + o, base + 40960 + D0);
  };

  // ---- frag read byte offsets (swizzled): row*64 + (kslc ^ ((row>>1)&3))*16
  int aoff[4], boff[4];
#pragma unroll
  for (int i = 0; i < 4; ++i) {
    const int rA = wm * 64 + i * 16 + l15;
    aoff[i] = rA * 64 + ((kslc ^ ((rA >> 1) & 3)) << 4);
    const int rB = wn * 64 + i * 16 + l15;
    boff[i] = rB * 64 + ((kslc ^ ((rB >> 1) & 3)) << 4);
  }

  ffrag acc[4][4];
  i32x4 accq[4][4];
#pragma unroll
  for (int m = 0; m < 4; ++m)
#pragma unroll
    for (int n = 0; n < 4; ++n) {
      acc[m][n] = {0.f, 0.f, 0.f, 0.f};
      accq[m][n] = {0, 0, 0, 0};
    }

  // prologue: A(0)+B(0) then B(1); vmcnt(2) -> tile0 landed, B(1) in flight
  stageA(0); stageB(0); stageB(1);
  asm volatile("s_waitcnt vmcnt(2)" ::: "memory");
  MEMFENCE();
  __builtin_amdgcn_s_barrier();

  bfrag Ahf[4], Bhf[4];
  i32x4 A8f[4], B8f[4];

  for (int t = 0; t < 128; ++t) {
    const char* base = SM + (t & 1) * 49152;
    // ---- P0: all 16 ds_reads (hh first -> compiler lgkm ladders);
    //      stage A[t+1]; MFMA hh
#pragma unroll
    for (int i = 0; i < 4; ++i)
      Ahf[i] = *reinterpret_cast<const bfrag*>(base + aoff[i]);
#pragma unroll
    for (int i = 0; i < 4; ++i)
      Bhf[i] = *reinterpret_cast<const bfrag*>(base + 32768 + boff[i]);
#pragma unroll
    for (int i = 0; i < 4; ++i)
      A8f[i] = *reinterpret_cast<const i32x4*>(base + 16384 + aoff[i]);
#pragma unroll
    for (int i = 0; i < 4; ++i)
      B8f[i] = *reinterpret_cast<const i32x4*>(base + 40960 + boff[i]);
    stageA(t + 1);
    MEMFENCE();
    __builtin_amdgcn_s_barrier();
    __builtin_amdgcn_s_setprio(1);
#pragma unroll
    for (int m = 0; m < 4; ++m)
#pragma unroll
      for (int n = 0; n < 4; ++n)
        acc[m][n] = __builtin_amdgcn_mfma_f32_16x16x32_bf16(
            Ahf[m], Bhf[n], acc[m][n], 0, 0, 0);
    __builtin_amdgcn_s_setprio(0);
    // drain the i8 ds_reads so P1's stageB can't overwrite them in flight
    asm volatile("s_waitcnt lgkmcnt(0)" ::: "memory");
    MEMFENCE();
    __builtin_amdgcn_s_barrier();
    // ---- P1: stage B[t+2]; MFMA i8 (frags already in regs)
    stageB(t + 2);
    MEMFENCE();
    __builtin_amdgcn_s_barrier();
    __builtin_amdgcn_s_setprio(1);
#pragma unroll
    for (int m = 0; m < 4; ++m)
#pragma unroll
      for (int n = 0; n < 4; ++n)
        accq[m][n] = __builtin_amdgcn_mfma_i32_16x16x64_i8(
            A8f[m], B8f[n], accq[m][n], 0, 0, 0);
    __builtin_amdgcn_s_setprio(0);
    // counted tile-end wait: A[t+1],B[t+1] landed; B[t+2] stays in flight
    if (t >= 126)
      asm volatile("s_waitcnt vmcnt(0)" ::: "memory");
    else
      asm volatile("s_waitcnt vmcnt(2)" ::: "memory");
    MEMFENCE();
    __builtin_amdgcn_s_barrier();
  }

  // epilogue: y = acc_hh + acc_lo * 2^-23 ; quantize; store bf16
  const int r0 = tm + wm * 64 + kslc * 4;
  const int c0 = tn + wn * 64 + l15;
#pragma unroll
  for (int m = 0; m < 4; ++m)
#pragma unroll
    for (int n = 0; n < 4; ++n)
#pragma unroll
      for (int r = 0; r < 4; ++r) {
        float y = acc[m][n][r] + (float)accq[m][n][r] * 0x1p-23f;
        float s = rintf((y + 1.0f) * 7.5f);  // RNE == jnp.round
        int idx = (int)s;
        idx = idx < 0 ? 0 : (idx > 15 ? 15 : idx);
        Yq[(size_t)(r0 + m * 16 + r) * N + (c0 + n * 16)] = f2bf(clut[idx]);
      }
}

// ============ GEMM2 (4-phase template, unchanged): out = yq @ Pi ==========
__global__ void __launch_bounds__(512, 2) gemm256_bt_kernel(
    const u16* __restrict__ A0, const u16* __restrict__ B0,
    float* __restrict__ Cout, int M, int N) {
  constexpr int NT = 64;
  __shared__ __align__(16) char SM[131072];
  const int tid = threadIdx.x;

  const int nbn = N >> 8;
  const int nwg = (M >> 8) * nbn;
  int wg = blockIdx.x;
  wg = (wg & 7) * (nwg >> 3) + (wg >> 3);
  const int tm = (wg / nbn) << 8;
  const int tn = (wg % nbn) << 8;

  const int lane = tid & 63;
  const int wv = tid >> 6;
  const int wm = wv >> 2;
  const int wn = wv & 3;
  const int l15 = lane & 15;
  const int kslc = lane >> 4;
  const int cXor = (lane & 7) << 4;

  const size_t thrOff =
      (size_t)(wv * 8 + (lane >> 3)) * 4096 + 8 * ((lane & 7) ^ (lane >> 3));
  const int ldsThr = wv * 1024 + lane * 16;

  auto STAGE = [&](int kind, int tau) {
    if (tau >= NT) return;
    const int b = tau & 1;
    const size_t ktE = (size_t)tau * 64;
    const u16* src;
    char* lds;
    if (kind >= 2) {
      const int idx = kind - 2;
      src = B0 + (size_t)(tn + idx * 128) * 4096 + ktE + thrOff;
      lds = SM + b * 65536 + 32768 + idx * 16384 + ldsThr;
    } else {
      src = A0 + (size_t)(tm + kind * 128) * 4096 + ktE + thrOff;
      lds = SM + b * 65536 + kind * 16384 + ldsThr;
    }
    GLDS16(src, lds);
    GLDS16(src + 262144, lds + 8192);
  };

#define LDSA(b, f, s)                                                      \
  (*reinterpret_cast<const bfrag*>(                                        \
      SM + (b) * 65536 + wm * 16384 + (((f) * 16 + l15) << 7) +            \
      ((((s) << 6) | (kslc << 4)) ^ cXor)))
#define LDSB(b, f, s)                                                      \
  (*reinterpret_cast<const bfrag*>(                                        \
      SM + (b) * 65536 + 32768 + (wn >> 1) * 16384 +                       \
      ((((wn & 1) * 64) + (f) * 16 + l15) << 7) +                          \
      ((((s) << 6) | (kslc << 4)) ^ cXor)))

  ffrag acc[8][4];
#pragma unroll
  for (int m = 0; m < 8; ++m)
#pragma unroll
    for (int n = 0; n < 4; ++n) acc[m][n] = {0.f, 0.f, 0.f, 0.f};

  STAGE(0, 0); STAGE(1, 0); STAGE(2, 0); STAGE(3, 0);
  STAGE(2, 1); STAGE(3, 1);
  asm volatile("s_waitcnt vmcnt(4)" ::: "memory");
  MEMFENCE();
  __builtin_amdgcn_s_barrier();

  bfrag Af[4], Bf[4];

  for (int t = 0; t < NT; ++t) {
    const int b = t & 1;
#pragma unroll
    for (int p = 0; p < 4; ++p) {
      const int s = p >> 1;
      const int mb = (p & 1) * 4;
      if ((p & 1) == 0) {
#pragma unroll
        for (int n = 0; n < 4; ++n) Bf[n] = LDSB(b, n, s);
      }
#pragma unroll
      for (int m = 0; m < 4; ++m) Af[m] = LDSA(b, mb + m, s);
      if (p == 0) STAGE(0, t + 1);
      else if (p == 1) STAGE(1, t + 1);
      else if (p == 3) { STAGE(2, t + 2); STAGE(3, t + 2); }
      MEMFENCE();
      __builtin_amdgcn_s_barrier();
      asm volatile("s_waitcnt lgkmcnt(0)" ::: "memory");
      __builtin_amdgcn_s_setprio(1);
#pragma unroll
      for (int m = 0; m < 4; ++m)
#pragma unroll
        for (int n = 0; n < 4; ++n)
          acc[mb + m][n] = __builtin_amdgcn_mfma_f32_16x16x32_bf16(
              Af[m], Bf[n], acc[mb + m][n], 0, 0, 0);
      __builtin_amdgcn_s_setprio(0);
      if (p == 3) {
        if (t == NT - 2)
          asm volatile("s_waitcnt vmcnt(0)" ::: "memory");
        else if (t < NT - 2)
          asm volatile("s_waitcnt vmcnt(4)" ::: "memory");
      }
      MEMFENCE();
      __builtin_amdgcn_s_barrier();
    }
  }

  const int r0 = tm + wm * 128 + kslc * 4;
  const int c0 = tn + wn * 64 + l15;
#pragma unroll
  for (int m = 0; m < 8; ++m)
#pragma unroll
    for (int n = 0; n < 4; ++n)
#pragma unroll
      for (int r = 0; r < 4; ++r)
        Cout[(size_t)(r0 + m * 16 + r) * N + (c0 + n * 16)] = acc[m][n][r];
#undef LDSA
#undef LDSB
}

extern "C" void kernel_launch(void* const* d_in, const int* in_sizes, int n_in,
                              void* d_out, int out_size, void* d_ws, size_t ws_size,
                              hipStream_t stream) {
  const float* x = (const float*)d_in[0];     // [8192][4096]
  const float* Pi = (const float*)d_in[1];    // [4096][4096]
  const float* cent = (const float*)d_in[2];  // [16]
  float* out = (float*)d_out;                 // [8192][4096]

  const size_t MB = (size_t)1 << 20;
  if (ws_size < 288 * MB) return;

  char* ws = (char*)d_ws;
  u16* x_hi  = (u16*)(ws + 0 * MB);     // 64MB  bf16(x)
  char* x_lo8 = (char*)(ws + 64 * MB);  // 32MB  i8(x - bf16(x)) * 2^13
  char* x_hi8 = (char*)(ws + 96 * MB);  // 32MB  i8(x) * 2^4
  u16* p_hi  = (u16*)(ws + 128 * MB);   // 32MB  bf16(Pi)
  char* p_hi8 = (char*)(ws + 160 * MB); // 16MB  i8(Pi) * 2^10
  char* p_lo8 = (char*)(ws + 176 * MB); // 16MB  i8(Pi - bf16(Pi)) * 2^19
  u16* piT   = (u16*)(ws + 192 * MB);   // 32MB  bf16(Pi^T)
  u16* yq    = (u16*)(ws + 224 * MB);   // 64MB  bf16(quantize(x @ Pi^T))

  prep_x_kernel<<<2048, 256, 0, stream>>>(x, x_hi, x_lo8, x_hi8,
                                          (long)NTOK * DD / 4);
  prep_pi_kernel<<<2048, 256, 0, stream>>>(Pi, p_hi, p_hi8, p_lo8,
                                           (long)DD * DD / 4);
  transpose_bf16_kernel<<<dim3(DD / 64, DD / 64), 256, 0, stream>>>(Pi, piT, DD, DD);

  // GEMM1 hybrid bf16+i8 + quantize -> yq   (grid 1024, 512 thr)
  gemm_i8lo_kernel<<<1024, 512, 0, stream>>>(
      x_hi, x_lo8, x_hi8, p_hi, p_hi8, p_lo8, yq, cent, NTOK, DD);
  // GEMM2: out = yq @ Pi
  gemm256_bt_kernel<<<512, 512, 0, stream>>>(yq, piT, out, NTOK, DD);
}

// Round 10
// 996.459 us; speedup vs baseline: 1.1537x; 1.1537x over previous
//
#include <hip/hip_runtime.h>
#include <hip/hip_bf16.h>

#define DD 4096
#define NTOK 8192

using u16 = unsigned short;

typedef __attribute__((ext_vector_type(8))) short bfrag;   // 8 bf16 = 4 VGPR
typedef __attribute__((ext_vector_type(4))) float ffrag;   // 16x16 MFMA C/D
typedef __attribute__((ext_vector_type(4))) float f32x4v;

// RNE float -> bf16 (bit math; matches numpy/JAX round-to-nearest-even)
__device__ __forceinline__ u16 f2bf(float f) {
  unsigned u = __float_as_uint(f);
  u += 0x7FFFu + ((u >> 16) & 1u);
  return (u16)(u >> 16);
}
__device__ __forceinline__ float bf2f(u16 u) {
  return __uint_as_float(((unsigned)u) << 16);
}

#define GLDS16(g, l)                                                  \
  __builtin_amdgcn_global_load_lds(                                   \
      (__attribute__((address_space(1))) const void*)(g),             \
      (__attribute__((address_space(3))) void*)(l), 16, 0, 0)

#define MEMFENCE() asm volatile("" ::: "memory")

// ---------------- split: f32 -> (bf16 hi, bf16 lo) ----------------
__global__ void __launch_bounds__(256) split_bf16_kernel(
    const float* __restrict__ in, u16* __restrict__ hi,
    u16* __restrict__ lo, long n4) {
  long i = (long)blockIdx.x * blockDim.x + threadIdx.x;
  const long stride = (long)gridDim.x * blockDim.x;
  for (; i < n4; i += stride) {
    f32x4v v = reinterpret_cast<const f32x4v*>(in)[i];
    u16 h[4], l[4];
#pragma unroll
    for (int j = 0; j < 4; ++j) {
      float f = v[j];
      u16 hb = f2bf(f);
      h[j] = hb;
      l[j] = f2bf(f - bf2f(hb));
    }
    ushort4 hv, lv;
    hv.x = h[0]; hv.y = h[1]; hv.z = h[2]; hv.w = h[3];
    lv.x = l[0]; lv.y = l[1]; lv.z = l[2]; lv.w = l[3];
    reinterpret_cast<ushort4*>(hi)[i] = hv;
    reinterpret_cast<ushort4*>(lo)[i] = lv;
  }
}

// ---------------- transpose f32 [R][C] -> bf16 [C][R] ----------------
__global__ void __launch_bounds__(256) transpose_bf16_kernel(
    const float* __restrict__ in, u16* __restrict__ out, int R, int C) {
  __shared__ u16 tile[64][65];
  const int bc = blockIdx.x << 6;
  const int br = blockIdx.y << 6;
  const int tc = threadIdx.x & 63;
  const int tr0 = threadIdx.x >> 6;
#pragma unroll
  for (int p = 0; p < 16; ++p) {
    int r = tr0 + (p << 2);
    tile[tc][r] = f2bf(in[(size_t)(br + r) * C + (bc + tc)]);
  }
  __syncthreads();
#pragma unroll
  for (int p = 0; p < 16; ++p) {
    int orow = tr0 + (p << 2);
    out[(size_t)(bc + orow) * R + (br + tc)] = tile[orow][tc];
  }
}

// ============ FUSED 3-term GEMM1 (16x16, 2-blocks/CU variant):
//   yq = quant( xh@ph^T + xl@ph^T + xh@pl^T )
// Tile 256x128, 4 waves (2Mx2N), per-wave 128x64 (identical per-wave math,
// frag formulas, and accumulation ORDER to the R6 known-good kernel).
// LDS SINGLE-buffered: Ah@0(16K), Al@16K(16K), Bh@32K(8K), Bl@40960(8K)
// = 48KB + clut -> 2 blocks/CU co-resident (the R6 config's 128KB forced
// 1 lockstep block/CU = the 49% MfmaUtil pin). Single-buffer safety:
// each unit overwritten only after lgkmcnt(0)+barrier following its LAST
// read (Ah staged P1, Al+Bh P3, Bl P4). Counted RAW waits (12 stage instr
// per tile): P3-end vmcnt(10) drains Bl[t]; tile-end vmcnt(2) drains
// Ah,Al,Bh[t+1], leaving Bl[t+1] in flight; t==127 P3-end vmcnt(0).
// Swizzle: R6 scheme unchanged (key=(byte>>7)&7 XOR into bits 4-6; dest
// linear, source pre-unswizzled; frag-read slot16 involution; 0 conflicts).
__global__ void __launch_bounds__(256, 2) gemm_fused3_kernel(
    const u16* __restrict__ Ah_, const u16* __restrict__ Al_,
    const u16* __restrict__ Bh_, const u16* __restrict__ Bl_,
    u16* __restrict__ Yq, const float* __restrict__ cent, int M, int N) {
  __shared__ __align__(16) char SM[49152];
  __shared__ float clut[16];
  const int tid = threadIdx.x;
  if (tid < 16) clut[tid] = cent[tid];

  // XCD swizzle (nwg=1024, %8==0 -> bijective)
  const int nbn = N >> 7;                 // 32
  const int nwg = (M >> 8) * nbn;         // 1024
  int wg = blockIdx.x;
  wg = (wg & 7) * (nwg >> 3) + (wg >> 3);
  const int tm = (wg / nbn) << 8;
  const int tn = (wg % nbn) << 7;

  const int lane = tid & 63;
  const int wv = tid >> 6;   // 0..3
  const int wm = wv >> 1;    // 0..1 (128-row panel)
  const int wn = wv & 1;     // 0..1 (64-col panel)
  const int l15 = lane & 15;
  const int kslc = lane >> 4;

  // staging: dest linear (per-instr 4KB pass), source pre-unswizzled.
  // key=(Dst>>7)&7 is q-invariant (q*4096 ≡ 0 mod 8 rows).
  const int key = (tid >> 3) & 7;
  const int baseL = (tid * 16) ^ (key << 4);
  const int srow = baseL >> 6;           // 0..63
  const int scol = (baseL & 63) >> 1;    // elems 0/8/16/24
  const size_t sA = (size_t)(tm + srow) * 4096 + scol;
  const size_t sB = (size_t)(tn + srow) * 4096 + scol;
  const int dOff = tid * 16;

  auto STAGE_A = [&](const u16* g, int ubase, int tau) {  // 256 rows, 4 instr
    if (tau >= 128) return;
    const u16* src = g + sA + (size_t)tau * 32;
    char* lds = SM + ubase + dOff;
#pragma unroll
    for (int q = 0; q < 4; ++q)
      GLDS16(src + (size_t)q * 64 * 4096, lds + q * 4096);
  };
  auto STAGE_B = [&](const u16* g, int ubase, int tau) {  // 128 rows, 2 instr
    if (tau >= 128) return;
    const u16* src = g + sB + (size_t)tau * 32;
    char* lds = SM + ubase + dOff;
    GLDS16(src, lds);
    GLDS16(src + (size_t)64 * 4096, lds + 4096);
  };

  // frag read offsets (R6 formulas; wn now 0..1 within 8KB B units)
  const int slot16 = ((((l15 & 1) << 2) | kslc) ^ (l15 >> 1)) << 4;
  const int aOff = wm * 8192 + (l15 >> 1) * 128 + slot16;
  const int bOff = wn * 4096 + (l15 >> 1) * 128 + slot16;

#define LDSF(ubase, off, f)                                              \
  (*reinterpret_cast<const bfrag*>(SM + (ubase) + (off) + (f) * 1024))

  ffrag acc[8][4];
#pragma unroll
  for (int m = 0; m < 8; ++m)
#pragma unroll
    for (int n = 0; n < 4; ++n) acc[m][n] = {0.f, 0.f, 0.f, 0.f};

  bfrag Ahf[8], Alf[4], Bhf[4], Blf[4];

  // prologue: stage tile 0 (12 instr); Ah,Al,Bh landed; Bl stays in flight
  STAGE_A(Ah_, 0, 0); STAGE_A(Al_, 16384, 0);
  STAGE_B(Bh_, 32768, 0); STAGE_B(Bl_, 40960, 0);
  asm volatile("s_waitcnt vmcnt(2)" ::: "memory");
  MEMFENCE();
  __builtin_amdgcn_s_barrier();

#define MFMA16(Aset, a0, Bset, mb)                                       \
  __builtin_amdgcn_s_setprio(1);                                         \
  _Pragma("unroll")                                                      \
  for (int m = 0; m < 4; ++m)                                            \
    _Pragma("unroll")                                                    \
    for (int n = 0; n < 4; ++n)                                          \
      acc[(mb) + m][n] = __builtin_amdgcn_mfma_f32_16x16x32_bf16(        \
          Aset[(a0) + m], Bset[n], acc[(mb) + m][n], 0, 0, 0);           \
  __builtin_amdgcn_s_setprio(0);

  for (int t = 0; t < 128; ++t) {
    // ---- P0: read Ah[0-3], Bh; MFMA hh m0-3
#pragma unroll
    for (int f = 0; f < 4; ++f) Ahf[f] = LDSF(0, aOff, f);
#pragma unroll
    for (int f = 0; f < 4; ++f) Bhf[f] = LDSF(32768, bOff, f);
    MEMFENCE();
    __builtin_amdgcn_s_barrier();
    MFMA16(Ahf, 0, Bhf, 0)
    MEMFENCE();
    __builtin_amdgcn_s_barrier();
    // ---- P1: read Ah[4-7]; drain+bar; STAGE Ah[t+1] (region free); MFMA
#pragma unroll
    for (int f = 0; f < 4; ++f) Ahf[4 + f] = LDSF(0, aOff, 4 + f);
    asm volatile("s_waitcnt lgkmcnt(0)" ::: "memory");
    MEMFENCE();
    __builtin_amdgcn_s_barrier();
    STAGE_A(Ah_, 0, t + 1);
    MFMA16(Ahf, 4, Bhf, 4)
    MEMFENCE();
    __builtin_amdgcn_s_barrier();
    // ---- P2: read Al[0-3]; MFMA lh m0-3
#pragma unroll
    for (int f = 0; f < 4; ++f) Alf[f] = LDSF(16384, aOff, f);
    MEMFENCE();
    __builtin_amdgcn_s_barrier();
    MFMA16(Alf, 0, Bhf, 0)
    MEMFENCE();
    __builtin_amdgcn_s_barrier();
    // ---- P3: read Al[4-7]; drain+bar; STAGE Al,Bh[t+1]; MFMA lh m4-7;
    //      counted drain of Bl[t] before P4-top reads
#pragma unroll
    for (int f = 0; f < 4; ++f) Alf[f] = LDSF(16384, aOff, 4 + f);
    asm volatile("s_waitcnt lgkmcnt(0)" ::: "memory");
    MEMFENCE();
    __builtin_amdgcn_s_barrier();
    STAGE_A(Al_, 16384, t + 1);
    STAGE_B(Bh_, 32768, t + 1);
    MFMA16(Alf, 0, Bhf, 4)
    if (t < 127)
      asm volatile("s_waitcnt vmcnt(10)" ::: "memory");  // Bl[t] landed
    else
      asm volatile("s_waitcnt vmcnt(0)" ::: "memory");   // tail
    MEMFENCE();
    __builtin_amdgcn_s_barrier();
    // ---- P4: read Bl; drain+bar; STAGE Bl[t+1]; MFMA hl (Ah reg-reuse);
    //      tile-end counted wait (Ah,Al,Bh[t+1] landed, Bl[t+1] in flight)
#pragma unroll
    for (int f = 0; f < 4; ++f) Blf[f] = LDSF(40960, bOff, f);
    asm volatile("s_waitcnt lgkmcnt(0)" ::: "memory");
    MEMFENCE();
    __builtin_amdgcn_s_barrier();
    STAGE_B(Bl_, 40960, t + 1);
    MFMA16(Ahf, 0, Blf, 0)
    MFMA16(Ahf, 4, Blf, 4)
    asm volatile("s_waitcnt vmcnt(2)" ::: "memory");
    MEMFENCE();
    __builtin_amdgcn_s_barrier();
  }

  // quant epilogue; C/D mapping: col = lane&15, row = (lane>>4)*4 + reg
  const int r0 = tm + wm * 128 + kslc * 4;
  const int c0 = tn + wn * 64 + l15;
#pragma unroll
  for (int m = 0; m < 8; ++m)
#pragma unroll
    for (int n = 0; n < 4; ++n)
#pragma unroll
      for (int r = 0; r < 4; ++r) {
        float y = acc[m][n][r];
        float s = rintf((y + 1.0f) * 7.5f);  // RNE == jnp.round
        int idx = (int)s;
        idx = idx < 0 ? 0 : (idx > 15 ? 15 : idx);
        Yq[(size_t)(r0 + m * 16 + r) * N + (c0 + n * 16)] = f2bf(clut[idx]);
      }
#undef LDSF
#undef MFMA16
}

// ============ GEMM2 (R6 4-phase template VERBATIM, known-good): out = yq @ Pi
__global__ void __launch_bounds__(512, 2) gemm256_bt_kernel(
    const u16* __restrict__ A0, const u16* __restrict__ B0,
    float* __restrict__ Cout, int M, int N) {
  constexpr int NT = 64;
  __shared__ __align__(16) char SM[131072];
  const int tid = threadIdx.x;

  const int nbn = N >> 8;
  const int nwg = (M >> 8) * nbn;
  int wg = blockIdx.x;
  wg = (wg & 7) * (nwg >> 3) + (wg >> 3);
  const int tm = (wg / nbn) << 8;
  const int tn = (wg % nbn) << 8;

  const int lane = tid & 63;
  const int wv = tid >> 6;
  const int wm = wv >> 2;
  const int wn = wv & 3;
  const int l15 = lane & 15;
  const int kslc = lane >> 4;
  const int cXor = (lane & 7) << 4;

  const size_t thrOff =
      (size_t)(wv * 8 + (lane >> 3)) * 4096 + 8 * ((lane & 7) ^ (lane >> 3));
  const int ldsThr = wv * 1024 + lane * 16;

  auto STAGE = [&](int kind, int tau) {
    if (tau >= NT) return;
    const int b = tau & 1;
    const size_t ktE = (size_t)tau * 64;
    const u16* src;
    char* lds;
    if (kind >= 2) {
      const int idx = kind - 2;
      src = B0 + (size_t)(tn + idx * 128) * 4096 + ktE + thrOff;
      lds = SM + b * 65536 + 32768 + idx * 16384 + ldsThr;
    } else {
      src = A0 + (size_t)(tm + kind * 128) * 4096 + ktE + thrOff;
      lds = SM + b * 65536 + kind * 16384 + ldsThr;
    }
    GLDS16(src, lds);
    GLDS16(src + 262144, lds + 8192);
  };

#define LDSA(b, f, s)                                                      \
  (*reinterpret_cast<const bfrag*>(                                        \
      SM + (b) * 65536 + wm * 16384 + (((f) * 16 + l15) << 7) +            \
      ((((s) << 6) | (kslc << 4)) ^ cXor)))
#define LDSB(b, f, s)                                                      \
  (*reinterpret_cast<const bfrag*>(                                        \
      SM + (b) * 65536 + 32768 + (wn >> 1) * 16384 +                       \
      ((((wn & 1) * 64) + (f) * 16 + l15) << 7) +                          \
      ((((s) << 6) | (kslc << 4)) ^ cXor)))

  ffrag acc[8][4];
#pragma unroll
  for (int m = 0; m < 8; ++m)
#pragma unroll
    for (int n = 0; n < 4; ++n) acc[m][n] = {0.f, 0.f, 0.f, 0.f};

  STAGE(0, 0); STAGE(1, 0); STAGE(2, 0); STAGE(3, 0);
  STAGE(2, 1); STAGE(3, 1);
  asm volatile("s_waitcnt vmcnt(4)" ::: "memory");
  MEMFENCE();
  __builtin_amdgcn_s_barrier();

  bfrag Af[4], Bf[4];

  for (int t = 0; t < NT; ++t) {
    const int b = t & 1;
#pragma unroll
    for (int p = 0; p < 4; ++p) {
      const int s = p >> 1;
      const int mb = (p & 1) * 4;
      if ((p & 1) == 0) {
#pragma unroll
        for (int n = 0; n < 4; ++n) Bf[n] = LDSB(b, n, s);
      }
#pragma unroll
      for (int m = 0; m < 4; ++m) Af[m] = LDSA(b, mb + m, s);
      if (p == 0) STAGE(0, t + 1);
      else if (p == 1) STAGE(1, t + 1);
      else if (p == 3) { STAGE(2, t + 2); STAGE(3, t + 2); }
      MEMFENCE();
      __builtin_amdgcn_s_barrier();
      asm volatile("s_waitcnt lgkmcnt(0)" ::: "memory");
      __builtin_amdgcn_s_setprio(1);
#pragma unroll
      for (int m = 0; m < 4; ++m)
#pragma unroll
        for (int n = 0; n < 4; ++n)
          acc[mb + m][n] = __builtin_amdgcn_mfma_f32_16x16x32_bf16(
              Af[m], Bf[n], acc[mb + m][n], 0, 0, 0);
      __builtin_amdgcn_s_setprio(0);
      if (p == 3) {
        if (t == NT - 2)
          asm volatile("s_waitcnt vmcnt(0)" ::: "memory");
        else if (t < NT - 2)
          asm volatile("s_waitcnt vmcnt(4)" ::: "memory");
      }
      MEMFENCE();
      __builtin_amdgcn_s_barrier();
    }
  }

  const int r0 = tm + wm * 128 + kslc * 4;
  const int c0 = tn + wn * 64 + l15;
#pragma unroll
  for (int m = 0; m < 8; ++m)
#pragma unroll
    for (int n = 0; n < 4; ++n)
#pragma unroll
      for (int r = 0; r < 4; ++r)
        Cout[(size_t)(r0 + m * 16 + r) * N + (c0 + n * 16)] = acc[m][n][r];
#undef LDSA
#undef LDSB
}

extern "C" void kernel_launch(void* const* d_in, const int* in_sizes, int n_in,
                              void* d_out, int out_size, void* d_ws, size_t ws_size,
                              hipStream_t stream) {
  const float* x = (const float*)d_in[0];     // [8192][4096]
  const float* Pi = (const float*)d_in[1];    // [4096][4096]
  const float* cent = (const float*)d_in[2];  // [16]
  float* out = (float*)d_out;                 // [8192][4096]

  const size_t MB = (size_t)1 << 20;
  if (ws_size < 288 * MB) return;

  char* ws = (char*)d_ws;
  u16* x_hi = (u16*)(ws + 0 * MB);    // 64MB  bf16(x)
  u16* x_lo = (u16*)(ws + 64 * MB);   // 64MB  bf16(x - x_hi)
  u16* p_hi = (u16*)(ws + 128 * MB);  // 32MB  bf16(Pi)
  u16* p_lo = (u16*)(ws + 160 * MB);  // 32MB  bf16(Pi - p_hi)
  u16* piT  = (u16*)(ws + 192 * MB);  // 32MB  bf16(Pi^T)
  u16* yq   = (u16*)(ws + 224 * MB);  // 64MB  bf16(quantize(x @ Pi^T))

  split_bf16_kernel<<<2048, 256, 0, stream>>>(x, x_hi, x_lo, (long)NTOK * DD / 4);
  split_bf16_kernel<<<1024, 256, 0, stream>>>(Pi, p_hi, p_lo, (long)DD * DD / 4);
  transpose_bf16_kernel<<<dim3(DD / 64, DD / 64), 256, 0, stream>>>(Pi, piT, DD, DD);

  // GEMM1 fused 3-term (16x16, 2-blocks/CU) + quantize -> yq
  gemm_fused3_kernel<<<1024, 256, 0, stream>>>(
      x_hi, x_lo, p_hi, p_lo, yq, cent, NTOK, DD);
  // GEMM2 (R6 verbatim): out = yq @ Pi
  gemm256_bt_kernel<<<512, 512, 0, stream>>>(yq, piT, out, NTOK, DD);
}